// Round 7
// baseline (525.345 us; speedup 1.0000x reference)
//
#include <hip/hip_runtime.h>
#include <hip/hip_bf16.h>

#define NTAGS 128
#define TLEN 512
#define BATCH 512
#define START_ID 0
#define END_ID 1

#define REP8(M) M(0) M(1) M(2) M(3) M(4) M(5) M(6) M(7)

// 512 threads/block, one block per batch. Thread j owns a QUARTER row:
// row r=j>>2, quarter q=j&3 -> E quarter = 8 named float4 = 32 VGPR (small
// enough that demotion to AGPR/scratch can't pay). amdgpu_waves_per_eu(4,4)
// pins the allocator to the grid-limited occupancy (2 blk/CU * 8 waves / 4
// SIMD = 4 waves/EU) so it has NO incentive to shrink VGPRs (R5/R6: LLVM
// chased 8 waves/EU and demoted E to AGPRs -> accvgpr round-trip per FMA).
// p layout: quarter q at float offset 36q -> per-instruction bank groups
// {4n,4n+4,4n+8,4n+12} are disjoint -> conflict-free (R6: 6.7e7 conflicts
// from half-offsets aliasing the same bank).
__global__ __launch_bounds__(512)
__attribute__((amdgpu_waves_per_eu(4, 4)))
void k_crf(
    const float* __restrict__ x, const int* __restrict__ tags,
    const float* __restrict__ mask, const float* __restrict__ transition,
    float* __restrict__ out)
{
  const int b = blockIdx.x;
  const int j = threadIdx.x;   // 0..511
  const int r = j >> 2;        // tag row 0..127
  const int q = j & 3;         // quarter of the row

  __shared__ __align__(16) float p_lds[2][144];  // quarters at 36q..36q+31
  __shared__ float red_lds[16];

  const float* xb = x + (size_t)b * TLEN * NTAGS;
  const float* mb = mask + b * TLEN;
  const int*   tb = tags + b * (TLEN + 1);

  // ---------------- gold score (fused prologue; one t per thread) --------
  {
    int to = tb[j + 1];
    int from = tb[j];
    float m = mb[j];
    float gs = (xb[(size_t)j * NTAGS + to] + transition[to * NTAGS + from]) * m;
    float msum = m;
    #pragma unroll
    for (int off = 32; off > 0; off >>= 1) {
      gs += __shfl_xor(gs, off);
      msum += __shfl_xor(msum, off);
    }
    int wid = j >> 6;
    if ((j & 63) == 0) { red_lds[wid] = gs; red_lds[8 + wid] = msum; }
  }
  __syncthreads();
  float gold_s = 0.f;
  if (j == 0) {
    float gt = 0.f, lt = 0.f;
    #pragma unroll
    for (int w = 0; w < 8; ++w) { gt += red_lds[w]; lt += red_lds[8 + w]; }
    int len = (int)lt;                        // exact: sum of 0/1 floats
    gold_s = gt + transition[END_ID * NTAGS + tb[len]];
  }

  // ------- E quarter-row -> 8 named float4 registers (32 VGPR) -------
  const float4* trow =
      reinterpret_cast<const float4*>(transition + r * NTAGS + q * 32);
#define E_DECL(n) float4 e##n;
  REP8(E_DECL)
#define E_INIT(n) { float4 tv = trow[n]; \
    e##n.x = __expf(tv.x); e##n.y = __expf(tv.y); \
    e##n.z = __expf(tv.z); e##n.w = __expf(tv.w); }
  REP8(E_INIT)
  const float etend = __expf(transition[END_ID * NTAGS + r]);

  // ---------------- forward scan ----------------
  float p = (r == START_ID) ? 1.0f : 0.0f;   // all 4 quarter-threads hold p
  float Clog = 0.0f;
  float s_cur = __expf(xb[r]);               // exp(emit_0[r])
  float m_cur = mb[0];

  const int widx = (r >> 5) * 36 + (r & 31); // row r's slot in padded layout
  int buf = 0;
  for (int t = 0; t < TLEN; ++t) {
    if (q == 0) p_lds[buf][widx] = p;        // 1 writer/row, conflict-free
    __syncthreads();                         // the only barrier per step

    // prefetch next step's emission/mask (hides under the dot)
    int tn = (t + 1 < TLEN) ? (t + 1) : (TLEN - 1);
    float emit_nxt = xb[(size_t)tn * NTAGS + r];
    float m_nxt = mb[tn];

    // quarter-dot over 32 entries; 4 addresses/instr in disjoint bank groups
    const float4* p4 =
        reinterpret_cast<const float4*>(p_lds[buf]) + q * 9;
    float a0 = 0.f, a1 = 0.f, a2 = 0.f, a3 = 0.f, S = 0.f;
#define E_FMA(n) { float4 pv = p4[n]; \
    a0 = fmaf(pv.x, e##n.x, a0); a1 = fmaf(pv.y, e##n.y, a1); \
    a2 = fmaf(pv.z, e##n.z, a2); a3 = fmaf(pv.w, e##n.w, a3); \
    S += pv.x; }
    REP8(E_FMA)
    float dot = (a0 + a1) + (a2 + a3);
    dot += __shfl_xor(dot, 1);               // combine 4 quarters
    dot += __shfl_xor(dot, 2);
    S += __shfl_xor(S, 1);                   // full subset-normalizer
    S += __shfl_xor(S, 2);

    float pn = dot * s_cur * (1.0f / S);
    bool upd = (m_cur > 0.0f);
    p = upd ? pn : p;
    Clog += upd ? __logf(S) : 0.0f;          // off critical path

    s_cur = __expf(emit_nxt);                // off critical path
    m_cur = m_nxt;
    buf ^= 1;
  }

  // ---------------- final logsumexp + output ----------------
  float v = (q == 0) ? p * etend : 0.0f;     // count each row once
  #pragma unroll
  for (int off = 32; off > 0; off >>= 1) v += __shfl_xor(v, off);
  if ((j & 63) == 0) red_lds[j >> 6] = v;    // ordered vs prologue by the
  __syncthreads();                           // 512 main-loop barriers
  if (j == 0) {
    float tot = 0.f;
    #pragma unroll
    for (int w = 0; w < 8; ++w) tot += red_lds[w];
    out[b] = Clog + __logf(tot) - gold_s;
  }
}

extern "C" void kernel_launch(void* const* d_in, const int* in_sizes, int n_in,
                              void* d_out, int out_size, void* d_ws, size_t ws_size,
                              hipStream_t stream) {
  const float* x          = (const float*)d_in[0];
  const int*   tags       = (const int*)d_in[1];
  const float* mask       = (const float*)d_in[2];
  const float* transition = (const float*)d_in[3];
  float* out = (float*)d_out;

  k_crf<<<BATCH, 512, 0, stream>>>(x, tags, mask, transition, out);
}